// Round 3
// baseline (579.412 us; speedup 1.0000x reference)
//
#include <hip/hip_runtime.h>
#include <hip/hip_bf16.h>

typedef __attribute__((ext_vector_type(8))) short s16x8;
typedef __attribute__((ext_vector_type(4))) float f32x4;

__device__ __forceinline__ unsigned short f2bf(float f){
    __hip_bfloat16 h = __float2bfloat16(f);
    return *reinterpret_cast<unsigned short*>(&h);
}

__device__ __forceinline__ int flab(int g){ return (g < 120) ? 0 : ((g < 124) ? 1 : 2); }

// async global->LDS, 16B per lane; LDS dest = wave-uniform base + lane*16
__device__ __forceinline__ void async16(const void* g, void* l){
    __builtin_amdgcn_global_load_lds(
        (const __attribute__((address_space(1))) unsigned int*)g,
        (__attribute__((address_space(3))) unsigned int*)l, 16, 0, 0);
}

// ---------------- weight fp32 -> bf16 ----------------
__global__ __launch_bounds__(256) void wconv_all(
    const float* __restrict__ w0, const float* __restrict__ w1,
    const float* __restrict__ w2, const float* __restrict__ w3,
    unsigned short* __restrict__ o0, unsigned short* __restrict__ o1,
    unsigned short* __restrict__ o2, unsigned short* __restrict__ o3)
{
    int i = blockIdx.x*256 + threadIdx.x;
    if (i < 110592) o0[i] = f2bf(w0[i]);   // qkv_w 576x192
    if (i < 36864)  o1[i] = f2bf(w1[i]);   // proj_w 192x192
    if (i < 147456) o2[i] = f2bf(w2[i]);   // fc1_w 768x192
    if (i < 147456) o3[i] = f2bf(w3[i]);   // fc2_w 192x768
}

// =====================================================================
// LN1 + shift + window partition + QKV GEMM, fused. One block per window.
// =====================================================================
__global__ __launch_bounds__(256) void lnqkv_kernel(
    const float* __restrict__ x, const float* __restrict__ g1, const float* __restrict__ b1,
    const unsigned short* __restrict__ wq, const float* __restrict__ qkvb,
    unsigned short* __restrict__ qo, unsigned short* __restrict__ ko,
    unsigned short* __restrict__ vo)
{
    __shared__ __attribute__((aligned(16))) unsigned short win[64*200];  // 25.6KB
    __shared__ __attribute__((aligned(16))) unsigned short Bs[64*200];   // 25.6KB (B-tile / T)
    const int b_ = blockIdx.x;
    const int bb = b_>>8, wi = b_&255, wh = wi>>4, ww = wi&15;
    const int tid = threadIdx.x;
    const int wv = tid>>6, lane = tid&63, lrow = lane&15, quad = lane>>4;

    // ---- LN1: thread t -> token n = t>>2, quarter q4 = t&3 (48 ch each) ----
    {
        const int n = tid>>2, q4 = tid&3;
        const int r = n>>3, c = n&7;
        const int hh = (wh*8 + r + 4)&127, wp = (ww*8 + c + 4)&127;  // roll(-4)
        const float* px = x + (((size_t)bb*128+hh)*128+wp)*192 + q4*48;
        float v[48];
        #pragma unroll
        for (int m=0;m<12;++m) *(float4*)(v+m*4) = *(const float4*)(px+m*4);
        float s = 0.f;
        #pragma unroll
        for (int k=0;k<48;++k) s += v[k];
        s += __shfl_xor(s,1); s += __shfl_xor(s,2);
        float mu = s*(1.0f/192.0f);
        float qv = 0.f;
        #pragma unroll
        for (int k=0;k<48;++k){ float d=v[k]-mu; qv += d*d; }
        qv += __shfl_xor(qv,1); qv += __shfl_xor(qv,2);
        float rstd = rsqrtf(qv*(1.0f/192.0f) + 1e-5f);
        const float* pg = g1 + q4*48;
        const float* pb = b1 + q4*48;
        unsigned short* pw = win + n*200 + q4*48;
        #pragma unroll
        for (int k=0;k<48;++k) pw[k] = f2bf((v[k]-mu)*rstd*pg[k] + pb[k]);
    }
    __syncthreads();

    // hoist A fragments (reused by every o-tile)
    s16x8 af[6];
    #pragma unroll
    for (int kc=0;kc<6;++kc)
        af[kc] = *(const s16x8*)(win + (wv*16+lrow)*200 + kc*32 + quad*8);

    for (int ot=0; ot<9; ++ot) {
        const int o0 = ot*64;
        __syncthreads();                       // Bs free (prev T reads done)
        #pragma unroll
        for (int t=0;t<6;++t) {
            int cid = tid + t*256;             // 0..1535, globally contiguous
            *(int4*)(Bs + (cid/24)*200 + (cid%24)*8) =
                *(const int4*)(wq + (size_t)o0*192 + cid*8);
        }
        __syncthreads();
        f32x4 acc[4];
        #pragma unroll
        for (int j=0;j<4;++j) acc[j] = (f32x4){0.f,0.f,0.f,0.f};
        #pragma unroll
        for (int kc=0;kc<6;++kc)
            #pragma unroll
            for (int j=0;j<4;++j) {
                s16x8 bf = *(const s16x8*)(Bs + (j*16+lrow)*200 + kc*32 + quad*8);
                acc[j] = __builtin_amdgcn_mfma_f32_16x16x32_bf16(af[kc], bf, acc[j], 0, 0, 0);
            }
        __syncthreads();                       // done reading Bs; reuse as T
        unsigned short* T = Bs;
        const int part = ot/3;                 // 0=q 1=k 2=v
        float bv[4];
        #pragma unroll
        for (int j=0;j<4;++j) bv[j] = qkvb[o0 + j*16 + lrow];

        if (part < 2) {
            const float scale = (part==0) ? 0.17677669529663687f : 1.0f;
            #pragma unroll
            for (int j=0;j<4;++j)
                #pragma unroll
                for (int rg=0;rg<4;++rg) {
                    int n2 = wv*16 + quad*4 + rg;
                    T[n2*72 + j*16 + lrow] = f2bf((acc[j][rg]+bv[j])*scale);
                }
            __syncthreads();
            unsigned short* dst = (part==0) ? qo : ko;
            #pragma unroll
            for (int t=0;t<2;++t) {
                int c = tid + t*256;
                int n2 = c>>3, blk = c&7;
                int o_in = o0 + blk*8 - part*192;
                int head = o_in>>5, d = o_in&31;
                *(int4*)(dst + (((size_t)b_*6+head)*64 + n2)*32 + d) =
                    *(const int4*)(T + n2*72 + blk*8);
            }
        } else {
            #pragma unroll
            for (int j=0;j<4;++j)
                #pragma unroll
                for (int rg=0;rg<4;++rg) {
                    int n2 = wv*16 + quad*4 + rg;
                    T[(j*16+lrow)*72 + n2] = f2bf(acc[j][rg]+bv[j]);
                }
            __syncthreads();
            #pragma unroll
            for (int t=0;t<2;++t) {
                int c = tid + t*256;
                int ol = c>>3, nb = (c&7)*8;
                int o_in = o0 + ol - 384;
                int head = o_in>>5, d = o_in&31;
                *(int4*)(vo + (((size_t)b_*6+head)*32 + d)*64 + nb) =
                    *(const int4*)(T + ol*72 + nb);
            }
        }
    }
}

// ---------------- windowed attention: 1 block/window, 6 waves = 6 heads ----------------
__global__ __launch_bounds__(384) void attn_kernel(
    const unsigned short* __restrict__ q, const unsigned short* __restrict__ k,
    const unsigned short* __restrict__ vT, const float* __restrict__ rpb,
    unsigned short* __restrict__ ao)
{
    __shared__ float rpb_s[1350];
    __shared__ __attribute__((aligned(16))) unsigned short p_lds[6*4608];
    const int b_ = blockIdx.x;
    const int h = threadIdx.x >> 6;
    const int lane = threadIdx.x & 63, lrow = lane & 15, quad = lane >> 4;
    for (int i = threadIdx.x; i < 1350; i += 384) rpb_s[i] = rpb[i];
    __syncthreads();

    const size_t hb = ((size_t)b_*6 + h)*2048;
    const unsigned short* qb = q  + hb;
    const unsigned short* kb = k  + hb;
    const unsigned short* vb = vT + hb;

    s16x8 qf[4], kf[4];
    #pragma unroll
    for (int i = 0; i < 4; ++i) qf[i] = *(const s16x8*)(qb + (i*16+lrow)*32 + quad*8);
    #pragma unroll
    for (int j = 0; j < 4; ++j) kf[j] = *(const s16x8*)(kb + (j*16+lrow)*32 + quad*8);

    const f32x4 zz = {0.f,0.f,0.f,0.f};
    f32x4 s[4][4];
    #pragma unroll
    for (int i = 0; i < 4; ++i)
        #pragma unroll
        for (int j = 0; j < 4; ++j)
            s[i][j] = __builtin_amdgcn_mfma_f32_16x16x32_bf16(qf[i], kf[j], zz, 0, 0, 0);

    const int wi = b_ & 255, wh = wi >> 4, ww = wi & 15;
    int labm[4];
    #pragma unroll
    for (int j = 0; j < 4; ++j) {
        int m = j*16 + lrow;
        labm[j] = flab(wh*8 + (m >> 3))*3 + flab(ww*8 + (m & 7));
    }
    unsigned short* pl = p_lds + h*4608;
    #pragma unroll
    for (int i = 0; i < 4; ++i) {
        #pragma unroll
        for (int rg = 0; rg < 4; ++rg) {
            int n = i*16 + quad*4 + rg;
            int rn = n >> 3, cn = n & 7;
            int labn = flab(wh*8 + rn)*3 + flab(ww*8 + cn);
            float vals[4];
            float vmax = -1e30f;
            #pragma unroll
            for (int j = 0; j < 4; ++j) {
                int m = j*16 + lrow;
                int idx = ((rn - (m >> 3) + 7)*15 + (cn - (m & 7) + 7))*6 + h;
                float val = s[i][j][rg] + rpb_s[idx];
                if (labn != labm[j]) val -= 100.f;
                vals[j] = val;
                vmax = fmaxf(vmax, val);
            }
            #pragma unroll
            for (int o = 1; o < 16; o <<= 1) vmax = fmaxf(vmax, __shfl_xor(vmax, o));
            float sum = 0.f;
            #pragma unroll
            for (int j = 0; j < 4; ++j) { vals[j] = __expf(vals[j] - vmax); sum += vals[j]; }
            #pragma unroll
            for (int o = 1; o < 16; o <<= 1) sum += __shfl_xor(sum, o);
            float inv = 1.f / sum;
            #pragma unroll
            for (int j = 0; j < 4; ++j) pl[n*72 + j*16 + lrow] = f2bf(vals[j]*inv);
        }
    }
    __syncthreads();

    f32x4 oacc[4][2];
    #pragma unroll
    for (int i = 0; i < 4; ++i) { oacc[i][0] = zz; oacc[i][1] = zz; }
    #pragma unroll
    for (int kc = 0; kc < 2; ++kc) {
        s16x8 vf[2];
        #pragma unroll
        for (int jd = 0; jd < 2; ++jd)
            vf[jd] = *(const s16x8*)(vb + (jd*16+lrow)*64 + kc*32 + quad*8);
        #pragma unroll
        for (int i = 0; i < 4; ++i) {
            s16x8 pf = *(const s16x8*)(pl + (i*16+lrow)*72 + kc*32 + quad*8);
            #pragma unroll
            for (int jd = 0; jd < 2; ++jd)
                oacc[i][jd] = __builtin_amdgcn_mfma_f32_16x16x32_bf16(pf, vf[jd], oacc[i][jd], 0, 0, 0);
        }
    }
    unsigned short* ob = ao + (size_t)b_*12288 + h*32;
    #pragma unroll
    for (int i = 0; i < 4; ++i)
        #pragma unroll
        for (int jd = 0; jd < 2; ++jd)
            #pragma unroll
            for (int rg = 0; rg < 4; ++rg) {
                int n = i*16 + quad*4 + rg;
                ob[(size_t)n*192 + jd*16 + lrow] = f2bf(oacc[i][jd][rg]);
            }
}

// =====================================================================
// proj GEMM (full O=192) + window-reverse/roll + residual + LN2, fused.
// =====================================================================
__global__ __launch_bounds__(256) void projln_kernel(
    const unsigned short* __restrict__ A, const unsigned short* __restrict__ W,
    const float* __restrict__ pbias, const float* __restrict__ x,
    const float* __restrict__ g2, const float* __restrict__ b2,
    float* __restrict__ x1, unsigned short* __restrict__ xln2)
{
    __shared__ __attribute__((aligned(16))) char smem[36864];
    unsigned short* As = (unsigned short*)smem;             // 64x72  (9.2KB)
    unsigned short* Bs = (unsigned short*)(smem + 9216);    // 192x72 (27.6KB)
    const int b_ = blockIdx.x;
    const int tid = threadIdx.x, wv = tid>>6, lane = tid&63;
    const int lrow = lane&15, quad = lane>>4;
    const size_t m0 = (size_t)b_*64;

    f32x4 acc[12];
    #pragma unroll
    for (int j=0;j<12;++j) acc[j] = (f32x4){0.f,0.f,0.f,0.f};

    for (int k0=0;k0<192;k0+=64) {
        __syncthreads();
        #pragma unroll
        for (int t=0;t<2;++t) {
            int cid = tid + t*256;
            *(int4*)(As + (cid>>3)*72 + (cid&7)*8) =
                *(const int4*)(A + (m0 + (cid>>3))*192 + k0 + (cid&7)*8);
        }
        #pragma unroll
        for (int t=0;t<6;++t) {
            int cid = tid + t*256;
            *(int4*)(Bs + (cid>>3)*72 + (cid&7)*8) =
                *(const int4*)(W + (size_t)(cid>>3)*192 + k0 + (cid&7)*8);
        }
        __syncthreads();
        #pragma unroll
        for (int kc=0;kc<2;++kc) {
            s16x8 af = *(const s16x8*)(As + (wv*16+lrow)*72 + kc*32 + quad*8);
            #pragma unroll
            for (int j=0;j<12;++j) {
                s16x8 bf = *(const s16x8*)(Bs + (j*16+lrow)*72 + kc*32 + quad*8);
                acc[j] = __builtin_amdgcn_mfma_f32_16x16x32_bf16(af, bf, acc[j], 0, 0, 0);
            }
        }
    }
    __syncthreads();

    const int bb = b_>>8, wi = b_&255, wh = wi>>4, ww = wi&15;
    float bv[12], gv[12], b2v[12];
    #pragma unroll
    for (int j=0;j<12;++j) {
        bv[j]  = pbias[j*16+lrow];
        gv[j]  = g2[j*16+lrow];
        b2v[j] = b2[j*16+lrow];
    }
    unsigned short* T = (unsigned short*)smem;   // 64x200 (25.6KB <= 36KB)
    #pragma unroll
    for (int rg=0;rg<4;++rg) {
        int n2 = wv*16 + quad*4 + rg;
        int r = n2>>3, c = n2&7;
        int hh = (wh*8+r+4)&127, wp = (ww*8+c+4)&127;   // roll(+4) back
        size_t tok = ((size_t)bb*128+hh)*128 + wp;
        float xv[12];
        float s = 0.f;
        #pragma unroll
        for (int j=0;j<12;++j) {
            float t = acc[j][rg] + bv[j] + x[tok*192 + j*16 + lrow];
            xv[j] = t; s += t;
        }
        #pragma unroll
        for (int o=1;o<16;o<<=1) s += __shfl_xor(s, o);
        float mu = s*(1.0f/192.0f);
        float qv = 0.f;
        #pragma unroll
        for (int j=0;j<12;++j){ float d = xv[j]-mu; qv += d*d; }
        #pragma unroll
        for (int o=1;o<16;o<<=1) qv += __shfl_xor(qv, o);
        float rstd = rsqrtf(qv*(1.0f/192.0f) + 1e-5f);
        #pragma unroll
        for (int j=0;j<12;++j) {
            x1[tok*192 + j*16 + lrow] = xv[j];
            T[n2*200 + j*16 + lrow] = f2bf((xv[j]-mu)*rstd*gv[j] + b2v[j]);
        }
    }
    __syncthreads();
    #pragma unroll
    for (int t=0;t<6;++t) {
        int cid = tid + t*256;                   // 0..1535
        int n2 = cid/24, blk = cid%24;
        int r = n2>>3, c = n2&7;
        int hh = (wh*8+r+4)&127, wp = (ww*8+c+4)&127;
        size_t tok = ((size_t)bb*128+hh)*128 + wp;
        *(int4*)(xln2 + tok*192 + blk*8) = *(const int4*)(T + n2*200 + blk*8);
    }
}

// =====================================================================
// 128x96 GEMM mainloop, BK=32, 3-buffer 2-deep pipeline (T3+T4):
// counted vmcnt (never 0 in steady state) + raw s_barrier keeps the
// NEXT tile's loads in flight across the barrier; load latency is
// covered by TWO compute phases. LDS 3x14KB = 42KB -> 3 blocks/CU.
// Swizzle: LDS(row, c) holds global(row, c ^ ((row>>1)&3)); 16-lane
// read phases hit all 8 bank-slots exactly 2x (free per m136).
// =====================================================================
template<int K>
__device__ __forceinline__ void mm128x96(
    const unsigned short* __restrict__ A, const unsigned short* __restrict__ W,
    size_t m0, int o0, unsigned short* As, unsigned short* Bs,
    f32x4 (&acc)[2][6])
{
    const int tid = threadIdx.x, wv = tid>>6, lane = tid&63;
    const int lrow = lane&15, quad = lane>>4;
    const int grow = lane>>2;                       // row within 16-row group
    const int gcb  = (lane&3) ^ ((lane>>3)&3);      // inverse-swizzled src col-block
    #pragma unroll
    for (int i=0;i<2;++i)
        #pragma unroll
        for (int j=0;j<6;++j) acc[i][j] = (f32x4){0.f,0.f,0.f,0.f};

    const unsigned short* Ab = A + (m0 + grow)*(size_t)K + gcb*8;
    const unsigned short* Wb = W + ((size_t)(o0 + grow))*K + gcb*8;

    // per-wave loads/tile: waves 0,1 -> 4; waves 2,3 -> 3
    auto issue = [&](int k0, int buf) {
        unsigned short* Ad = As + buf*4096;
        unsigned short* Bd = Bs + buf*3072;
        async16(Ab + (size_t)(wv*16)*K + k0,     Ad + wv*512);
        async16(Ab + (size_t)((wv+4)*16)*K + k0, Ad + (wv+4)*512);
        async16(Wb + (size_t)(wv*16)*K + k0,     Bd + wv*512);
        if (wv < 2)
            async16(Wb + (size_t)((wv+4)*16)*K + k0, Bd + (wv+4)*512);
    };
    auto compute = [&](int buf) {
        const unsigned short* Ac = As + buf*4096;
        const unsigned short* Bc = Bs + buf*3072;
        const int rs = (quad ^ ((lrow>>1)&3)) << 3;
        s16x8 af[2], bf[6];
        #pragma unroll
        for (int i=0;i<2;++i)
            af[i] = *(const s16x8*)(Ac + (wv*32 + i*16 + lrow)*32 + rs);
        #pragma unroll
        for (int j=0;j<6;++j)
            bf[j] = *(const s16x8*)(Bc + (j*16 + lrow)*32 + rs);
        #pragma unroll
        for (int i=0;i<2;++i)
            #pragma unroll
            for (int j=0;j<6;++j)
                acc[i][j] = __builtin_amdgcn_mfma_f32_16x16x32_bf16(af[i], bf[j], acc[i][j], 0, 0, 0);
    };

    constexpr int NT = K/32;
    issue(0, 0);
    issue(32, 1);
    int cur = 0;
    for (int t = 0; t < NT-2; ++t) {
        if (wv < 2) asm volatile("s_waitcnt vmcnt(4)" ::: "memory");
        else        asm volatile("s_waitcnt vmcnt(3)" ::: "memory");
        __builtin_amdgcn_s_barrier();
        asm volatile("" ::: "memory");
        int nb = cur + 2; if (nb >= 3) nb -= 3;     // buf of tile t+2 (its readers passed barrier)
        issue((t+2)*32, nb);
        asm volatile("" ::: "memory");
        compute(cur);
        cur = (cur == 2) ? 0 : cur + 1;
    }
    // peeled: tile NT-2 (tile NT-1 still in flight)
    if (wv < 2) asm volatile("s_waitcnt vmcnt(4)" ::: "memory");
    else        asm volatile("s_waitcnt vmcnt(3)" ::: "memory");
    __builtin_amdgcn_s_barrier();
    asm volatile("" ::: "memory");
    compute(cur);
    cur = (cur == 2) ? 0 : cur + 1;
    // peeled: tile NT-1 (drain)
    asm volatile("s_waitcnt vmcnt(0)" ::: "memory");
    __builtin_amdgcn_s_barrier();
    asm volatile("" ::: "memory");
    compute(cur);
}

// ---------------- FC1 + bias + tanh-GELU -> h1 bf16 ----------------
// grid 8192 = 1024 m-tiles x 8 o-tiles; XCD-swizzled so the 8 o-tiles
// sharing an A-tile run consecutively on one XCD (L2 hits).
__global__ __launch_bounds__(256, 3) void gemm_fc1_kernel(
    const unsigned short* __restrict__ A, const unsigned short* __restrict__ Wm,
    const float* __restrict__ bias, unsigned short* __restrict__ h1)
{
    __shared__ __attribute__((aligned(16))) char smem[43008];
    unsigned short* As = (unsigned short*)smem;             // 3 x 8KB
    unsigned short* Bs = (unsigned short*)(smem + 24576);   // 3 x 6KB
    const int bid = blockIdx.x;
    const int virt = (bid & 7)*1024 + (bid >> 3);           // 8192 % 8 == 0: bijective
    const size_t m0 = (size_t)(virt >> 3)*128;
    const int o0 = (virt & 7)*96;
    f32x4 acc[2][6];
    mm128x96<192>(A, Wm, m0, o0, As, Bs, acc);
    const int tid = threadIdx.x, wv = tid>>6, lane = tid&63;
    const int lrow = lane&15, quad = lane>>4;
    float bv[6];
    #pragma unroll
    for (int j=0;j<6;++j) bv[j] = bias[o0 + j*16 + lrow];
    __syncthreads();                              // mainloop LDS reads done
    unsigned short* T = (unsigned short*)smem;    // 128x104 (26.6KB <= 42KB)
    #pragma unroll
    for (int i=0;i<2;++i)
        #pragma unroll
        for (int j=0;j<6;++j)
            #pragma unroll
            for (int rg=0;rg<4;++rg) {
                int ml = wv*32 + i*16 + quad*4 + rg;
                float v = acc[i][j][rg] + bv[j];
                // tanh-GELU: v * sigmoid(1.5957691*v + 0.07135482*v^3)
                float v2 = v*v;
                float z = v*(1.5957691216057308f + 0.07135481627f*v2);
                float r = v * __builtin_amdgcn_rcpf(1.f + __expf(-z));
                T[ml*104 + j*16 + lrow] = f2bf(r);
            }
    __syncthreads();
    #pragma unroll
    for (int t=0;t<6;++t) {
        int c = tid + t*256;                      // 0..1535 = 128 rows x 12 chunks
        int row = c/12, blk = c%12;
        *(int4*)(h1 + (m0+row)*768 + o0 + blk*8) = *(const int4*)(T + row*104 + blk*8);
    }
}

// ---------------- FC2 (K=768) + bias + residual -> out fp32 ----------------
// grid 2048 = 1024 m-tiles x 2 o-tiles; XCD-swizzled (2048 % 8 == 0).
__global__ __launch_bounds__(256, 3) void gemm_fc2_kernel(
    const unsigned short* __restrict__ A, const unsigned short* __restrict__ Wm,
    const float* __restrict__ bias, const float* __restrict__ x1, float* __restrict__ out)
{
    __shared__ __attribute__((aligned(16))) char smem[43008];
    unsigned short* As = (unsigned short*)smem;
    unsigned short* Bs = (unsigned short*)(smem + 24576);
    const int bid = blockIdx.x;
    const int virt = (bid & 7)*256 + (bid >> 3);
    const size_t m0 = (size_t)(virt >> 1)*128;
    const int o0 = (virt & 1)*96;
    f32x4 acc[2][6];
    mm128x96<768>(A, Wm, m0, o0, As, Bs, acc);
    const int tid = threadIdx.x, wv = tid>>6, lane = tid&63;
    const int lrow = lane&15, quad = lane>>4;
    float bv[6];
    #pragma unroll
    for (int j=0;j<6;++j) bv[j] = bias[o0 + j*16 + lrow];
    float* T = (float*)smem;                      // 64x100 fp32 (25.6KB <= 42KB)
    #pragma unroll
    for (int p=0;p<2;++p) {
        __syncthreads();
        if ((wv>>1) == p) {
            int wl = wv&1;
            #pragma unroll
            for (int i=0;i<2;++i)
                #pragma unroll
                for (int j=0;j<6;++j)
                    #pragma unroll
                    for (int rg=0;rg<4;++rg)
                        T[(wl*32 + i*16 + quad*4 + rg)*100 + j*16 + lrow] = acc[i][j][rg] + bv[j];
        }
        __syncthreads();
        #pragma unroll
        for (int t=0;t<6;++t) {
            int c = tid + t*256;                  // 0..1535 = 64 rows x 24 float4
            int row = c/24, blk = c%24;
            size_t ad = (m0 + p*64 + row)*192 + o0 + blk*4;
            float4 v = *(const float4*)(T + row*100 + blk*4);
            float4 rx = *(const float4*)(x1 + ad);
            v.x += rx.x; v.y += rx.y; v.z += rx.z; v.w += rx.w;
            *(float4*)(out + ad) = v;
        }
    }
}

extern "C" void kernel_launch(void* const* d_in, const int* in_sizes, int n_in,
                              void* d_out, int out_size, void* d_ws, size_t ws_size,
                              hipStream_t stream)
{
    const float* x      = (const float*)d_in[0];
    const float* g1     = (const float*)d_in[1];
    const float* b1     = (const float*)d_in[2];
    const float* qkv_w  = (const float*)d_in[3];
    const float* qkv_b  = (const float*)d_in[4];
    const float* rpb    = (const float*)d_in[5];
    const float* proj_w = (const float*)d_in[6];
    const float* proj_b = (const float*)d_in[7];
    const float* g2     = (const float*)d_in[8];
    const float* b2     = (const float*)d_in[9];
    const float* fc1_w  = (const float*)d_in[10];
    const float* fc1_b  = (const float*)d_in[11];
    const float* fc2_w  = (const float*)d_in[12];
    const float* fc2_b  = (const float*)d_in[13];
    float* out = (float*)d_out;
    char* ws = (char*)d_ws;

    if (ws_size < 353206272ULL) return;

    unsigned short* qbuf  = (unsigned short*)(ws + 0);          // 50.3MB
    unsigned short* kbuf  = (unsigned short*)(ws + 50331648);   // 50.3MB
    unsigned short* vbuf  = (unsigned short*)(ws + 100663296);  // 50.3MB (vT)
    unsigned short* attnO = (unsigned short*)(ws + 150994944);  // 50.3MB
    float*          x1    = (float*)        (ws + 201326592);   // 100.7MB
    unsigned short* xln2  = (unsigned short*)(ws + 301989888);  // 50.3MB
    unsigned short* wq    = (unsigned short*)(ws + 352321536);
    unsigned short* wp    = (unsigned short*)(ws + 352321536 + 221184);
    unsigned short* w1    = (unsigned short*)(ws + 352321536 + 221184 + 73728);
    unsigned short* w2    = (unsigned short*)(ws + 352321536 + 221184 + 73728 + 294912);
    unsigned short* h1    = (unsigned short*)(ws + 0);          // 201.3MB overlays q,k,v,attnO

    wconv_all<<<576, 256, 0, stream>>>(qkv_w, proj_w, fc1_w, fc2_w, wq, wp, w1, w2);
    lnqkv_kernel<<<2048, 256, 0, stream>>>(x, g1, b1, wq, qkv_b, qbuf, kbuf, vbuf);
    attn_kernel<<<2048, 384, 0, stream>>>(qbuf, kbuf, vbuf, rpb, attnO);
    projln_kernel<<<2048, 256, 0, stream>>>(attnO, wp, proj_b, x, g2, b2, x1, xln2);
    gemm_fc1_kernel<<<8192, 256, 0, stream>>>(xln2, w1, fc1_b, h1);
    gemm_fc2_kernel<<<2048, 256, 0, stream>>>(h1, w2, fc2_b, x1, out);
}

// Round 4
// 564.317 us; speedup vs baseline: 1.0267x; 1.0267x over previous
//
#include <hip/hip_runtime.h>
#include <hip/hip_bf16.h>

typedef __attribute__((ext_vector_type(8))) short s16x8;
typedef __attribute__((ext_vector_type(4))) float f32x4;

__device__ __forceinline__ unsigned short f2bf(float f){
    __hip_bfloat16 h = __float2bfloat16(f);
    return *reinterpret_cast<unsigned short*>(&h);
}

__device__ __forceinline__ int flab(int g){ return (g < 120) ? 0 : ((g < 124) ? 1 : 2); }

// async global->LDS, 16B per lane; LDS dest = wave-uniform base + lane*16
__device__ __forceinline__ void async16(const void* g, void* l){
    __builtin_amdgcn_global_load_lds(
        (const __attribute__((address_space(1))) unsigned int*)g,
        (__attribute__((address_space(3))) unsigned int*)l, 16, 0, 0);
}

// ---------------- weight fp32 -> bf16 ----------------
__global__ __launch_bounds__(256) void wconv_all(
    const float* __restrict__ w0, const float* __restrict__ w1,
    const float* __restrict__ w2, const float* __restrict__ w3,
    unsigned short* __restrict__ o0, unsigned short* __restrict__ o1,
    unsigned short* __restrict__ o2, unsigned short* __restrict__ o3)
{
    int i = blockIdx.x*256 + threadIdx.x;
    if (i < 110592) o0[i] = f2bf(w0[i]);   // qkv_w 576x192
    if (i < 36864)  o1[i] = f2bf(w1[i]);   // proj_w 192x192
    if (i < 147456) o2[i] = f2bf(w2[i]);   // fc1_w 768x192
    if (i < 147456) o3[i] = f2bf(w3[i]);   // fc2_w 192x768
}

// =====================================================================
// LN1 + shift + window partition + QKV GEMM, fused. One block per window.
// =====================================================================
__global__ __launch_bounds__(256) void lnqkv_kernel(
    const float* __restrict__ x, const float* __restrict__ g1, const float* __restrict__ b1,
    const unsigned short* __restrict__ wq, const float* __restrict__ qkvb,
    unsigned short* __restrict__ qo, unsigned short* __restrict__ ko,
    unsigned short* __restrict__ vo)
{
    __shared__ __attribute__((aligned(16))) unsigned short win[64*200];  // 25.6KB
    __shared__ __attribute__((aligned(16))) unsigned short Bs[64*200];   // 25.6KB (B-tile / T)
    const int b_ = blockIdx.x;
    const int bb = b_>>8, wi = b_&255, wh = wi>>4, ww = wi&15;
    const int tid = threadIdx.x;
    const int wv = tid>>6, lane = tid&63, lrow = lane&15, quad = lane>>4;

    // ---- LN1: thread t -> token n = t>>2, quarter q4 = t&3 (48 ch each) ----
    {
        const int n = tid>>2, q4 = tid&3;
        const int r = n>>3, c = n&7;
        const int hh = (wh*8 + r + 4)&127, wp = (ww*8 + c + 4)&127;  // roll(-4)
        const float* px = x + (((size_t)bb*128+hh)*128+wp)*192 + q4*48;
        float v[48];
        #pragma unroll
        for (int m=0;m<12;++m) *(float4*)(v+m*4) = *(const float4*)(px+m*4);
        float s = 0.f;
        #pragma unroll
        for (int k=0;k<48;++k) s += v[k];
        s += __shfl_xor(s,1); s += __shfl_xor(s,2);
        float mu = s*(1.0f/192.0f);
        float qv = 0.f;
        #pragma unroll
        for (int k=0;k<48;++k){ float d=v[k]-mu; qv += d*d; }
        qv += __shfl_xor(qv,1); qv += __shfl_xor(qv,2);
        float rstd = rsqrtf(qv*(1.0f/192.0f) + 1e-5f);
        const float* pg = g1 + q4*48;
        const float* pb = b1 + q4*48;
        unsigned short* pw = win + n*200 + q4*48;
        #pragma unroll
        for (int k=0;k<48;++k) pw[k] = f2bf((v[k]-mu)*rstd*pg[k] + pb[k]);
    }
    __syncthreads();

    // hoist A fragments (reused by every o-tile)
    s16x8 af[6];
    #pragma unroll
    for (int kc=0;kc<6;++kc)
        af[kc] = *(const s16x8*)(win + (wv*16+lrow)*200 + kc*32 + quad*8);

    for (int ot=0; ot<9; ++ot) {
        const int o0 = ot*64;
        __syncthreads();                       // Bs free (prev T reads done)
        #pragma unroll
        for (int t=0;t<6;++t) {
            int cid = tid + t*256;             // 0..1535, globally contiguous
            *(int4*)(Bs + (cid/24)*200 + (cid%24)*8) =
                *(const int4*)(wq + (size_t)o0*192 + cid*8);
        }
        __syncthreads();
        f32x4 acc[4];
        #pragma unroll
        for (int j=0;j<4;++j) acc[j] = (f32x4){0.f,0.f,0.f,0.f};
        #pragma unroll
        for (int kc=0;kc<6;++kc)
            #pragma unroll
            for (int j=0;j<4;++j) {
                s16x8 bf = *(const s16x8*)(Bs + (j*16+lrow)*200 + kc*32 + quad*8);
                acc[j] = __builtin_amdgcn_mfma_f32_16x16x32_bf16(af[kc], bf, acc[j], 0, 0, 0);
            }
        __syncthreads();                       // done reading Bs; reuse as T
        unsigned short* T = Bs;
        const int part = ot/3;                 // 0=q 1=k 2=v
        float bv[4];
        #pragma unroll
        for (int j=0;j<4;++j) bv[j] = qkvb[o0 + j*16 + lrow];

        if (part < 2) {
            const float scale = (part==0) ? 0.17677669529663687f : 1.0f;
            #pragma unroll
            for (int j=0;j<4;++j)
                #pragma unroll
                for (int rg=0;rg<4;++rg) {
                    int n2 = wv*16 + quad*4 + rg;
                    T[n2*72 + j*16 + lrow] = f2bf((acc[j][rg]+bv[j])*scale);
                }
            __syncthreads();
            unsigned short* dst = (part==0) ? qo : ko;
            #pragma unroll
            for (int t=0;t<2;++t) {
                int c = tid + t*256;
                int n2 = c>>3, blk = c&7;
                int o_in = o0 + blk*8 - part*192;
                int head = o_in>>5, d = o_in&31;
                *(int4*)(dst + (((size_t)b_*6+head)*64 + n2)*32 + d) =
                    *(const int4*)(T + n2*72 + blk*8);
            }
        } else {
            #pragma unroll
            for (int j=0;j<4;++j)
                #pragma unroll
                for (int rg=0;rg<4;++rg) {
                    int n2 = wv*16 + quad*4 + rg;
                    T[(j*16+lrow)*72 + n2] = f2bf(acc[j][rg]+bv[j]);
                }
            __syncthreads();
            #pragma unroll
            for (int t=0;t<2;++t) {
                int c = tid + t*256;
                int ol = c>>3, nb = (c&7)*8;
                int o_in = o0 + ol - 384;
                int head = o_in>>5, d = o_in&31;
                *(int4*)(vo + (((size_t)b_*6+head)*32 + d)*64 + nb) =
                    *(const int4*)(T + ol*72 + nb);
            }
        }
    }
}

// ---------------- windowed attention: 1 block/window, 6 waves = 6 heads ----------------
__global__ __launch_bounds__(384) void attn_kernel(
    const unsigned short* __restrict__ q, const unsigned short* __restrict__ k,
    const unsigned short* __restrict__ vT, const float* __restrict__ rpb,
    unsigned short* __restrict__ ao)
{
    __shared__ float rpb_s[1350];
    __shared__ __attribute__((aligned(16))) unsigned short p_lds[6*4608];
    const int b_ = blockIdx.x;
    const int h = threadIdx.x >> 6;
    const int lane = threadIdx.x & 63, lrow = lane & 15, quad = lane >> 4;
    for (int i = threadIdx.x; i < 1350; i += 384) rpb_s[i] = rpb[i];
    __syncthreads();

    const size_t hb = ((size_t)b_*6 + h)*2048;
    const unsigned short* qb = q  + hb;
    const unsigned short* kb = k  + hb;
    const unsigned short* vb = vT + hb;

    s16x8 qf[4], kf[4];
    #pragma unroll
    for (int i = 0; i < 4; ++i) qf[i] = *(const s16x8*)(qb + (i*16+lrow)*32 + quad*8);
    #pragma unroll
    for (int j = 0; j < 4; ++j) kf[j] = *(const s16x8*)(kb + (j*16+lrow)*32 + quad*8);

    const f32x4 zz = {0.f,0.f,0.f,0.f};
    f32x4 s[4][4];
    #pragma unroll
    for (int i = 0; i < 4; ++i)
        #pragma unroll
        for (int j = 0; j < 4; ++j)
            s[i][j] = __builtin_amdgcn_mfma_f32_16x16x32_bf16(qf[i], kf[j], zz, 0, 0, 0);

    const int wi = b_ & 255, wh = wi >> 4, ww = wi & 15;
    int labm[4];
    #pragma unroll
    for (int j = 0; j < 4; ++j) {
        int m = j*16 + lrow;
        labm[j] = flab(wh*8 + (m >> 3))*3 + flab(ww*8 + (m & 7));
    }
    unsigned short* pl = p_lds + h*4608;
    #pragma unroll
    for (int i = 0; i < 4; ++i) {
        #pragma unroll
        for (int rg = 0; rg < 4; ++rg) {
            int n = i*16 + quad*4 + rg;
            int rn = n >> 3, cn = n & 7;
            int labn = flab(wh*8 + rn)*3 + flab(ww*8 + cn);
            float vals[4];
            float vmax = -1e30f;
            #pragma unroll
            for (int j = 0; j < 4; ++j) {
                int m = j*16 + lrow;
                int idx = ((rn - (m >> 3) + 7)*15 + (cn - (m & 7) + 7))*6 + h;
                float val = s[i][j][rg] + rpb_s[idx];
                if (labn != labm[j]) val -= 100.f;
                vals[j] = val;
                vmax = fmaxf(vmax, val);
            }
            #pragma unroll
            for (int o = 1; o < 16; o <<= 1) vmax = fmaxf(vmax, __shfl_xor(vmax, o));
            float sum = 0.f;
            #pragma unroll
            for (int j = 0; j < 4; ++j) { vals[j] = __expf(vals[j] - vmax); sum += vals[j]; }
            #pragma unroll
            for (int o = 1; o < 16; o <<= 1) sum += __shfl_xor(sum, o);
            float inv = 1.f / sum;
            #pragma unroll
            for (int j = 0; j < 4; ++j) pl[n*72 + j*16 + lrow] = f2bf(vals[j]*inv);
        }
    }
    __syncthreads();

    f32x4 oacc[4][2];
    #pragma unroll
    for (int i = 0; i < 4; ++i) { oacc[i][0] = zz; oacc[i][1] = zz; }
    #pragma unroll
    for (int kc = 0; kc < 2; ++kc) {
        s16x8 vf[2];
        #pragma unroll
        for (int jd = 0; jd < 2; ++jd)
            vf[jd] = *(const s16x8*)(vb + (jd*16+lrow)*64 + kc*32 + quad*8);
        #pragma unroll
        for (int i = 0; i < 4; ++i) {
            s16x8 pf = *(const s16x8*)(pl + (i*16+lrow)*72 + kc*32 + quad*8);
            #pragma unroll
            for (int jd = 0; jd < 2; ++jd)
                oacc[i][jd] = __builtin_amdgcn_mfma_f32_16x16x32_bf16(pf, vf[jd], oacc[i][jd], 0, 0, 0);
        }
    }
    unsigned short* ob = ao + (size_t)b_*12288 + h*32;
    #pragma unroll
    for (int i = 0; i < 4; ++i)
        #pragma unroll
        for (int jd = 0; jd < 2; ++jd)
            #pragma unroll
            for (int rg = 0; rg < 4; ++rg) {
                int n = i*16 + quad*4 + rg;
                ob[(size_t)n*192 + jd*16 + lrow] = f2bf(oacc[i][jd][rg]);
            }
}

// =====================================================================
// 64x192 pipelined GEMM mainloop for projln: async16 + fixed swizzle +
// 2-buffer. A 64x32 (4KB) + B 192x32 (12KB) per buffer = 32KB LDS ->
// 5 blocks/CU. Swizzle: LDS(row,cb) = global(row, cb ^ ((row>>1)&3)).
// =====================================================================
__device__ __forceinline__ void mm64x192(
    const unsigned short* __restrict__ A, const unsigned short* __restrict__ W,
    size_t m0, unsigned short* As, unsigned short* Bs, f32x4 (&acc)[12])
{
    const int tid = threadIdx.x, wv = tid>>6, lane = tid&63;
    const int lrow = lane&15, quad = lane>>4;
    const int grow = lane>>2;                       // row within 16-row group
    const int gcb  = (lane&3) ^ ((lane>>3)&3);      // inverse-swizzled src col-block
    #pragma unroll
    for (int j=0;j<12;++j) acc[j] = (f32x4){0.f,0.f,0.f,0.f};

    const unsigned short* Ab = A + (m0 + grow)*192 + gcb*8;
    const unsigned short* Wb = W + (size_t)grow*192 + gcb*8;

    auto issue = [&](int k0, unsigned short* Ad, unsigned short* Bd) {
        async16(Ab + (size_t)(wv*16)*192 + k0,     Ad + wv*512);     // A: 4 groups
        async16(Wb + (size_t)(wv*16)*192 + k0,     Bd + wv*512);     // B: 12 groups
        async16(Wb + (size_t)((wv+4)*16)*192 + k0, Bd + (wv+4)*512);
        async16(Wb + (size_t)((wv+8)*16)*192 + k0, Bd + (wv+8)*512);
    };
    issue(0, As, Bs);
    int cur = 0;
    for (int k0=0; k0<192; k0+=32) {
        __syncthreads();                       // tile cur landed; prev reads done
        if (k0+32 < 192) issue(k0+32, As + (cur^1)*2048, Bs + (cur^1)*6144);
        const unsigned short* Ac = As + cur*2048;
        const unsigned short* Bc = Bs + cur*6144;
        const int rs = (quad ^ ((lrow>>1)&3)) << 3;
        s16x8 af = *(const s16x8*)(Ac + (wv*16+lrow)*32 + rs);
        #pragma unroll
        for (int j=0;j<12;++j) {
            s16x8 bf = *(const s16x8*)(Bc + (j*16+lrow)*32 + rs);
            acc[j] = __builtin_amdgcn_mfma_f32_16x16x32_bf16(af, bf, acc[j], 0, 0, 0);
        }
        cur ^= 1;
    }
}

// =====================================================================
// proj GEMM (full O=192) + window-reverse/roll + residual + LN2, fused.
// =====================================================================
__global__ __launch_bounds__(256) void projln_kernel(
    const unsigned short* __restrict__ A, const unsigned short* __restrict__ W,
    const float* __restrict__ pbias, const float* __restrict__ x,
    const float* __restrict__ g2, const float* __restrict__ b2,
    float* __restrict__ x1, unsigned short* __restrict__ xln2)
{
    __shared__ __attribute__((aligned(16))) char smem[32768];
    unsigned short* As = (unsigned short*)smem;             // 2 x 4KB
    unsigned short* Bs = (unsigned short*)(smem + 8192);    // 2 x 12KB
    const int b_ = blockIdx.x;
    const int tid = threadIdx.x, wv = tid>>6, lane = tid&63;
    const int lrow = lane&15, quad = lane>>4;
    const size_t m0 = (size_t)b_*64;

    f32x4 acc[12];
    mm64x192(A, W, m0, As, Bs, acc);
    __syncthreads();

    const int bb = b_>>8, wi = b_&255, wh = wi>>4, ww = wi&15;
    float bv[12], gv[12], b2v[12];
    #pragma unroll
    for (int j=0;j<12;++j) {
        bv[j]  = pbias[j*16+lrow];
        gv[j]  = g2[j*16+lrow];
        b2v[j] = b2[j*16+lrow];
    }
    unsigned short* T = (unsigned short*)smem;   // 64x200 (25.6KB <= 32KB)
    #pragma unroll
    for (int rg=0;rg<4;++rg) {
        int n2 = wv*16 + quad*4 + rg;
        int r = n2>>3, c = n2&7;
        int hh = (wh*8+r+4)&127, wp = (ww*8+c+4)&127;   // roll(+4) back
        size_t tok = ((size_t)bb*128+hh)*128 + wp;
        float xv[12];
        float s = 0.f;
        #pragma unroll
        for (int j=0;j<12;++j) {
            float t = acc[j][rg] + bv[j] + x[tok*192 + j*16 + lrow];
            xv[j] = t; s += t;
        }
        #pragma unroll
        for (int o=1;o<16;o<<=1) s += __shfl_xor(s, o);
        float mu = s*(1.0f/192.0f);
        float qv = 0.f;
        #pragma unroll
        for (int j=0;j<12;++j){ float d = xv[j]-mu; qv += d*d; }
        #pragma unroll
        for (int o=1;o<16;o<<=1) qv += __shfl_xor(qv, o);
        float rstd = rsqrtf(qv*(1.0f/192.0f) + 1e-5f);
        #pragma unroll
        for (int j=0;j<12;++j) {
            x1[tok*192 + j*16 + lrow] = xv[j];
            T[n2*200 + j*16 + lrow] = f2bf((xv[j]-mu)*rstd*gv[j] + b2v[j]);
        }
    }
    __syncthreads();
    #pragma unroll
    for (int t=0;t<6;++t) {
        int cid = tid + t*256;                   // 0..1535
        int n2 = cid/24, blk = cid%24;
        int r = n2>>3, c = n2&7;
        int hh = (wh*8+r+4)&127, wp = (ww*8+c+4)&127;
        size_t tok = ((size_t)bb*128+hh)*128 + wp;
        *(int4*)(xln2 + tok*192 + blk*8) = *(const int4*)(T + n2*200 + blk*8);
    }
}

// =====================================================================
// 128x96 GEMM mainloop, BK=32, 2-buffer (r2 structure) + FIXED swizzle:
// LDS(row,cb) = global(row, cb ^ ((row>>1)&3)). 28KB LDS -> 5 blocks/CU.
// One __syncthreads per tile; loads of tile t+1 overlap compute of t
// plus cross-block TLP.
// =====================================================================
template<int K>
__device__ __forceinline__ void mm128x96(
    const unsigned short* __restrict__ A, const unsigned short* __restrict__ W,
    size_t m0, int o0, unsigned short* As, unsigned short* Bs,
    f32x4 (&acc)[2][6])
{
    const int tid = threadIdx.x, wv = tid>>6, lane = tid&63;
    const int lrow = lane&15, quad = lane>>4;
    const int grow = lane>>2;                       // row within 16-row group
    const int gcb  = (lane&3) ^ ((lane>>3)&3);      // inverse-swizzled src col-block
    #pragma unroll
    for (int i=0;i<2;++i)
        #pragma unroll
        for (int j=0;j<6;++j) acc[i][j] = (f32x4){0.f,0.f,0.f,0.f};

    const unsigned short* Ab = A + (m0 + grow)*(size_t)K + gcb*8;
    const unsigned short* Wb = W + ((size_t)(o0 + grow))*K + gcb*8;

    // per-wave loads/tile: waves 0,1 -> 4; waves 2,3 -> 3
    auto issue = [&](int k0, unsigned short* Ad, unsigned short* Bd) {
        async16(Ab + (size_t)(wv*16)*K + k0,     Ad + wv*512);
        async16(Ab + (size_t)((wv+4)*16)*K + k0, Ad + (wv+4)*512);
        async16(Wb + (size_t)(wv*16)*K + k0,     Bd + wv*512);
        if (wv < 2)
            async16(Wb + (size_t)((wv+4)*16)*K + k0, Bd + (wv+4)*512);
    };
    issue(0, As, Bs);
    int cur = 0;
    for (int k0=0; k0<K; k0+=32) {
        __syncthreads();                       // tile cur landed; prev reads done
        if (k0+32 < K) issue(k0+32, As + (cur^1)*4096, Bs + (cur^1)*3072);
        const unsigned short* Ac = As + cur*4096;
        const unsigned short* Bc = Bs + cur*3072;
        const int rs = (quad ^ ((lrow>>1)&3)) << 3;
        s16x8 af[2], bf[6];
        #pragma unroll
        for (int i=0;i<2;++i)
            af[i] = *(const s16x8*)(Ac + (wv*32 + i*16 + lrow)*32 + rs);
        #pragma unroll
        for (int j=0;j<6;++j)
            bf[j] = *(const s16x8*)(Bc + (j*16 + lrow)*32 + rs);
        #pragma unroll
        for (int i=0;i<2;++i)
            #pragma unroll
            for (int j=0;j<6;++j)
                acc[i][j] = __builtin_amdgcn_mfma_f32_16x16x32_bf16(af[i], bf[j], acc[i][j], 0, 0, 0);
        cur ^= 1;
    }
}

// ---------------- FC1 + bias + tanh-GELU -> h1 bf16 ----------------
// grid 8192 = 1024 m-tiles x 8 o-tiles; XCD-swizzled so the 8 o-tiles
// sharing an A-tile run consecutively on one XCD (L2 hits).
__global__ __launch_bounds__(256, 4) void gemm_fc1_kernel(
    const unsigned short* __restrict__ A, const unsigned short* __restrict__ Wm,
    const float* __restrict__ bias, unsigned short* __restrict__ h1)
{
    __shared__ __attribute__((aligned(16))) char smem[28672];
    unsigned short* As = (unsigned short*)smem;             // 2 x 8KB
    unsigned short* Bs = (unsigned short*)(smem + 16384);   // 2 x 6KB
    const int bid = blockIdx.x;
    const int virt = (bid & 7)*1024 + (bid >> 3);           // 8192 % 8 == 0: bijective
    const size_t m0 = (size_t)(virt >> 3)*128;
    const int o0 = (virt & 7)*96;
    f32x4 acc[2][6];
    mm128x96<192>(A, Wm, m0, o0, As, Bs, acc);
    const int tid = threadIdx.x, wv = tid>>6, lane = tid&63;
    const int lrow = lane&15, quad = lane>>4;
    float bv[6];
    #pragma unroll
    for (int j=0;j<6;++j) bv[j] = bias[o0 + j*16 + lrow];
    __syncthreads();                              // mainloop LDS reads done
    unsigned short* T = (unsigned short*)smem;    // 128x104 (26.6KB <= 28KB)
    #pragma unroll
    for (int i=0;i<2;++i)
        #pragma unroll
        for (int j=0;j<6;++j)
            #pragma unroll
            for (int rg=0;rg<4;++rg) {
                int ml = wv*32 + i*16 + quad*4 + rg;
                float v = acc[i][j][rg] + bv[j];
                // tanh-GELU: v * sigmoid(1.5957691*v + 0.07135482*v^3)
                float v2 = v*v;
                float z = v*(1.5957691216057308f + 0.07135481627f*v2);
                float r = v * __builtin_amdgcn_rcpf(1.f + __expf(-z));
                T[ml*104 + j*16 + lrow] = f2bf(r);
            }
    __syncthreads();
    #pragma unroll
    for (int t=0;t<6;++t) {
        int c = tid + t*256;                      // 0..1535 = 128 rows x 12 chunks
        int row = c/12, blk = c%12;
        *(int4*)(h1 + (m0+row)*768 + o0 + blk*8) = *(const int4*)(T + row*104 + blk*8);
    }
}

// ---------------- FC2 (K=768) + bias + residual -> out fp32 ----------------
// grid 2048 = 1024 m-tiles x 2 o-tiles; XCD-swizzled (2048 % 8 == 0).
__global__ __launch_bounds__(256, 4) void gemm_fc2_kernel(
    const unsigned short* __restrict__ A, const unsigned short* __restrict__ Wm,
    const float* __restrict__ bias, const float* __restrict__ x1, float* __restrict__ out)
{
    __shared__ __attribute__((aligned(16))) char smem[28672];
    unsigned short* As = (unsigned short*)smem;
    unsigned short* Bs = (unsigned short*)(smem + 16384);
    const int bid = blockIdx.x;
    const int virt = (bid & 7)*256 + (bid >> 3);
    const size_t m0 = (size_t)(virt >> 1)*128;
    const int o0 = (virt & 1)*96;
    f32x4 acc[2][6];
    mm128x96<768>(A, Wm, m0, o0, As, Bs, acc);
    const int tid = threadIdx.x, wv = tid>>6, lane = tid&63;
    const int lrow = lane&15, quad = lane>>4;
    float bv[6];
    #pragma unroll
    for (int j=0;j<6;++j) bv[j] = bias[o0 + j*16 + lrow];
    float* T = (float*)smem;                      // 64x100 fp32 (25.6KB <= 28KB)
    #pragma unroll
    for (int p=0;p<2;++p) {
        __syncthreads();
        if ((wv>>1) == p) {
            int wl = wv&1;
            #pragma unroll
            for (int i=0;i<2;++i)
                #pragma unroll
                for (int j=0;j<6;++j)
                    #pragma unroll
                    for (int rg=0;rg<4;++rg)
                        T[(wl*32 + i*16 + quad*4 + rg)*100 + j*16 + lrow] = acc[i][j][rg] + bv[j];
        }
        __syncthreads();
        #pragma unroll
        for (int t=0;t<6;++t) {
            int c = tid + t*256;                  // 0..1535 = 64 rows x 24 float4
            int row = c/24, blk = c%24;
            size_t ad = (m0 + p*64 + row)*192 + o0 + blk*4;
            float4 v = *(const float4*)(T + row*100 + blk*4);
            float4 rx = *(const float4*)(x1 + ad);
            v.x += rx.x; v.y += rx.y; v.z += rx.z; v.w += rx.w;
            *(float4*)(out + ad) = v;
        }
    }
}

extern "C" void kernel_launch(void* const* d_in, const int* in_sizes, int n_in,
                              void* d_out, int out_size, void* d_ws, size_t ws_size,
                              hipStream_t stream)
{
    const float* x      = (const float*)d_in[0];
    const float* g1     = (const float*)d_in[1];
    const float* b1     = (const float*)d_in[2];
    const float* qkv_w  = (const float*)d_in[3];
    const float* qkv_b  = (const float*)d_in[4];
    const float* rpb    = (const float*)d_in[5];
    const float* proj_w = (const float*)d_in[6];
    const float* proj_b = (const float*)d_in[7];
    const float* g2     = (const float*)d_in[8];
    const float* b2     = (const float*)d_in[9];
    const float* fc1_w  = (const float*)d_in[10];
    const float* fc1_b  = (const float*)d_in[11];
    const float* fc2_w  = (const float*)d_in[12];
    const float* fc2_b  = (const float*)d_in[13];
    float* out = (float*)d_out;
    char* ws = (char*)d_ws;

    if (ws_size < 353206272ULL) return;

    unsigned short* qbuf  = (unsigned short*)(ws + 0);          // 50.3MB
    unsigned short* kbuf  = (unsigned short*)(ws + 50331648);   // 50.3MB
    unsigned short* vbuf  = (unsigned short*)(ws + 100663296);  // 50.3MB (vT)
    unsigned short* attnO = (unsigned short*)(ws + 150994944);  // 50.3MB
    float*          x1    = (float*)        (ws + 201326592);   // 100.7MB
    unsigned short* xln2  = (unsigned short*)(ws + 301989888);  // 50.3MB
    unsigned short* wq    = (unsigned short*)(ws + 352321536);
    unsigned short* wp    = (unsigned short*)(ws + 352321536 + 221184);
    unsigned short* w1    = (unsigned short*)(ws + 352321536 + 221184 + 73728);
    unsigned short* w2    = (unsigned short*)(ws + 352321536 + 221184 + 73728 + 294912);
    unsigned short* h1    = (unsigned short*)(ws + 0);          // 201.3MB overlays q,k,v,attnO

    wconv_all<<<576, 256, 0, stream>>>(qkv_w, proj_w, fc1_w, fc2_w, wq, wp, w1, w2);
    lnqkv_kernel<<<2048, 256, 0, stream>>>(x, g1, b1, wq, qkv_b, qbuf, kbuf, vbuf);
    attn_kernel<<<2048, 384, 0, stream>>>(qbuf, kbuf, vbuf, rpb, attnO);
    projln_kernel<<<2048, 256, 0, stream>>>(attnO, wp, proj_b, x, g2, b2, x1, xln2);
    gemm_fc1_kernel<<<8192, 256, 0, stream>>>(xln2, w1, fc1_b, h1);
    gemm_fc2_kernel<<<2048, 256, 0, stream>>>(h1, w2, fc2_b, x1, out);
}